// Round 2
// baseline (381.647 us; speedup 1.0000x reference)
//
#include <hip/hip_runtime.h>
#include <hip/hip_bf16.h>

// All float tensors are fp32 (per reference dtypes); edge_index is int32.

// ---------------- CSR build (graph is identical for all 3 layers) ----------------

__global__ void count_kernel(const int* __restrict__ ei, int E, int N, int* __restrict__ cnt) {
  int t = blockIdx.x * blockDim.x + threadIdx.x;
  if (t >= E + N) return;
  int dst = (t < E) ? ei[E + t] : (t - E);
  atomicAdd(&cnt[dst], 1);
}

// single block of 1024 threads; handles N <= 16384. cnt_cursor: in=counts, out=offsets copy
__global__ void scan_kernel(int* __restrict__ cnt_cursor, int* __restrict__ off, int N) {
  __shared__ int sdata[1024];
  const int CH = 16;
  int tid = threadIdx.x;
  int base = tid * CH;
  int lc[CH];
  int lsum = 0;
#pragma unroll
  for (int j = 0; j < CH; j++) {
    int idx = base + j;
    int v = (idx < N) ? cnt_cursor[idx] : 0;
    lc[j] = v;
    lsum += v;
  }
  sdata[tid] = lsum;
  __syncthreads();
  for (int o = 1; o < 1024; o <<= 1) {
    int v = (tid >= o) ? sdata[tid - o] : 0;
    __syncthreads();
    sdata[tid] += v;
    __syncthreads();
  }
  int run = sdata[tid] - lsum;  // exclusive prefix of this thread's chunk
#pragma unroll
  for (int j = 0; j < CH; j++) {
    int idx = base + j;
    if (idx < N) { off[idx] = run; cnt_cursor[idx] = run; }
    run += lc[j];
  }
  if (tid == 1023) off[N] = sdata[1023];
}

__global__ void fill_kernel(const int* __restrict__ ei, int E, int N,
                            int* __restrict__ cursor, int* __restrict__ csr) {
  int t = blockIdx.x * blockDim.x + threadIdx.x;
  if (t >= E + N) return;
  int src, dst;
  if (t < E) { src = ei[t]; dst = ei[E + t]; }
  else       { src = t - E; dst = t - E; }
  int pos = atomicAdd(&cursor[dst], 1);
  csr[pos] = src;
}

// ---------------- GEMM: H[M,256] = X[M,256] @ W[256,256], fp32 ----------------
// 64x64 tile per 256-thread block, 4x4 micro-tile per thread, K staged 16 at a time in LDS.

__global__ void gemm_kernel(const float* __restrict__ X, const float* __restrict__ W,
                            float* __restrict__ H, int M) {
  const int K = 256, NN = 256;
  __shared__ float As[64][17];
  __shared__ float Bs[16][65];
  int tid = threadIdx.x;         // 256 threads
  int tx = tid & 15, ty = tid >> 4;
  int m0 = blockIdx.x * 64, n0 = blockIdx.y * 64;

  int lm = tid >> 2;             // 0..63 row within A tile
  int lk = (tid & 3) * 4;        // 0,4,8,12
  int bk = tid >> 4;             // 0..15 row of B tile (k)
  int bn = (tid & 15) * 4;       // col group of B tile

  float c[4][4] = {};

  for (int k0 = 0; k0 < K; k0 += 16) {
    int gm = m0 + lm;
    if (gm < M) {
      const float4 v = *(const float4*)&X[gm * K + k0 + lk];
      As[lm][lk + 0] = v.x; As[lm][lk + 1] = v.y;
      As[lm][lk + 2] = v.z; As[lm][lk + 3] = v.w;
    } else {
#pragma unroll
      for (int j = 0; j < 4; j++) As[lm][lk + j] = 0.0f;
    }
    {
      const float4 w = *(const float4*)&W[(k0 + bk) * NN + n0 + bn];
      Bs[bk][bn + 0] = w.x; Bs[bk][bn + 1] = w.y;
      Bs[bk][bn + 2] = w.z; Bs[bk][bn + 3] = w.w;
    }
    __syncthreads();
#pragma unroll
    for (int kk = 0; kk < 16; kk++) {
      float a[4], b[4];
#pragma unroll
      for (int i = 0; i < 4; i++) a[i] = As[ty + 16 * i][kk];
#pragma unroll
      for (int j = 0; j < 4; j++) b[j] = Bs[kk][tx + 16 * j];
#pragma unroll
      for (int i = 0; i < 4; i++)
#pragma unroll
        for (int j = 0; j < 4; j++) c[i][j] += a[i] * b[j];
    }
    __syncthreads();
  }
#pragma unroll
  for (int i = 0; i < 4; i++) {
    int gm = m0 + ty + 16 * i;
    if (gm < M) {
#pragma unroll
      for (int j = 0; j < 4; j++) H[gm * NN + n0 + tx + 16 * j] = c[i][j];
    }
  }
}

// ---------------- attention coefficients: a_s/a_d [N,4] ----------------

__global__ void attn_kernel(const float* __restrict__ H, const float* __restrict__ att_s,
                            const float* __restrict__ att_d, float* __restrict__ a_s,
                            float* __restrict__ a_d, int N) {
  int t = blockIdx.x * blockDim.x + threadIdx.x;
  if (t >= N * 4) return;
  int n = t >> 2, h = t & 3;
  const float* hp = H + n * 256 + h * 64;
  float ss = 0.0f, sd = 0.0f;
#pragma unroll 8
  for (int c = 0; c < 64; c++) {
    float v = hp[c];
    ss += v * att_s[h * 64 + c];
    sd += v * att_d[h * 64 + c];
  }
  a_s[t] = ss;
  a_d[t] = sd;
}

// ---------------- per-dst segment softmax + aggregation + bias + ELU ----------------
// one wave (64 lanes) per destination node; lane = channel within head.

__global__ void agg_kernel(const float* __restrict__ H, const float* __restrict__ a_s,
                           const float* __restrict__ a_d, const int* __restrict__ off,
                           const int* __restrict__ csr, const float* __restrict__ bias,
                           float* __restrict__ Out) {
  int n = blockIdx.x;
  int lane = threadIdx.x;  // 64
  int o0 = off[n], o1 = off[n + 1];
  int deg = o1 - o0;

  float ad[4];
#pragma unroll
  for (int h = 0; h < 4; h++) ad[h] = a_d[n * 4 + h];

  // pass 1: per-head max over incoming edges
  float mx[4] = {-1e30f, -1e30f, -1e30f, -1e30f};
  for (int i = lane; i < deg; i += 64) {
    int s = csr[o0 + i];
#pragma unroll
    for (int h = 0; h < 4; h++) {
      float e = a_s[s * 4 + h] + ad[h];
      e = (e > 0.0f) ? e : 0.2f * e;
      mx[h] = fmaxf(mx[h], e);
    }
  }
#pragma unroll
  for (int h = 0; h < 4; h++)
#pragma unroll
    for (int d = 1; d < 64; d <<= 1) mx[h] = fmaxf(mx[h], __shfl_xor(mx[h], d, 64));

  // pass 2: denom
  float sm[4] = {0.0f, 0.0f, 0.0f, 0.0f};
  for (int i = lane; i < deg; i += 64) {
    int s = csr[o0 + i];
#pragma unroll
    for (int h = 0; h < 4; h++) {
      float e = a_s[s * 4 + h] + ad[h];
      e = (e > 0.0f) ? e : 0.2f * e;
      sm[h] += __expf(e - mx[h]);
    }
  }
#pragma unroll
  for (int h = 0; h < 4; h++) {
#pragma unroll
    for (int d = 1; d < 64; d <<= 1) sm[h] += __shfl_xor(sm[h], d, 64);
  }
  float inv[4];
#pragma unroll
  for (int h = 0; h < 4; h++) inv[h] = 1.0f / (sm[h] + 1e-16f);

  // pass 3: weighted aggregation. chunk weights into LDS, edges sequential, lanes = channels.
  __shared__ int ssrc[64];
  __shared__ float sw[64][4];
  float acc[4] = {0.0f, 0.0f, 0.0f, 0.0f};
  for (int base = 0; base < deg; base += 64) {
    int cnt = min(64, deg - base);
    if (lane < cnt) {
      int s = csr[o0 + base + lane];
      ssrc[lane] = s;
#pragma unroll
      for (int h = 0; h < 4; h++) {
        float e = a_s[s * 4 + h] + ad[h];
        e = (e > 0.0f) ? e : 0.2f * e;
        sw[lane][h] = __expf(e - mx[h]) * inv[h];
      }
    }
    __syncthreads();
    for (int i = 0; i < cnt; i++) {
      const float* hp = H + ssrc[i] * 256;
      acc[0] += sw[i][0] * hp[lane];
      acc[1] += sw[i][1] * hp[64 + lane];
      acc[2] += sw[i][2] * hp[128 + lane];
      acc[3] += sw[i][3] * hp[192 + lane];
    }
    __syncthreads();
  }

#pragma unroll
  for (int h = 0; h < 4; h++) {
    float v = acc[h] + bias[h * 64 + lane];
    v = (v > 0.0f) ? v : expm1f(v);  // ELU
    Out[n * 256 + h * 64 + lane] = v;
  }
}

// ---------------- launch ----------------

extern "C" void kernel_launch(void* const* d_in, const int* in_sizes, int n_in,
                              void* d_out, int out_size, void* d_ws, size_t ws_size,
                              hipStream_t stream) {
  const int N = in_sizes[0] / 256;   // 10000 nodes
  const int E = in_sizes[1] / 2;     // 320000 edges
  const int Etot = E + N;            // + self loops

  const float* x  = (const float*)d_in[0];
  const int*   ei = (const int*)d_in[1];
  const float* Wl[3]  = {(const float*)d_in[2], (const float*)d_in[6], (const float*)d_in[10]};
  const float* asl[3] = {(const float*)d_in[3], (const float*)d_in[7], (const float*)d_in[11]};
  const float* adl[3] = {(const float*)d_in[4], (const float*)d_in[8], (const float*)d_in[12]};
  const float* bl[3]  = {(const float*)d_in[5], (const float*)d_in[9], (const float*)d_in[13]};
  float* out = (float*)d_out;

  // workspace carve (fp32 intermediates), 256B aligned
  char* p = (char*)d_ws;
  auto carve = [&](size_t bytes) {
    char* r = p;
    p += (bytes + 255) & ~size_t(255);
    return r;
  };
  int*   off    = (int*)carve(sizeof(int) * (N + 1));
  int*   cursor = (int*)carve(sizeof(int) * N);
  int*   csr    = (int*)carve(sizeof(int) * Etot);
  float* a_s    = (float*)carve(sizeof(float) * N * 4);
  float* a_d    = (float*)carve(sizeof(float) * N * 4);
  float* h_buf  = (float*)carve(sizeof(float) * N * 256);
  float* x_buf  = (float*)carve(sizeof(float) * N * 256);
  (void)ws_size; (void)n_in; (void)out_size;

  // CSR build (once; same graph for all 3 layers)
  hipMemsetAsync(cursor, 0, sizeof(int) * N, stream);
  int eb = (Etot + 255) / 256;
  count_kernel<<<eb, 256, 0, stream>>>(ei, E, N, cursor);
  scan_kernel<<<1, 1024, 0, stream>>>(cursor, off, N);
  fill_kernel<<<eb, 256, 0, stream>>>(ei, E, N, cursor, csr);

  const int bm = (N + 63) / 64;
  dim3 ggrid(bm, 4);
  int ab = (N * 4 + 255) / 256;

  // layer 1
  gemm_kernel<<<ggrid, 256, 0, stream>>>(x, Wl[0], h_buf, N);
  attn_kernel<<<ab, 256, 0, stream>>>(h_buf, asl[0], adl[0], a_s, a_d, N);
  agg_kernel<<<N, 64, 0, stream>>>(h_buf, a_s, a_d, off, csr, bl[0], x_buf);
  // layer 2
  gemm_kernel<<<ggrid, 256, 0, stream>>>(x_buf, Wl[1], h_buf, N);
  attn_kernel<<<ab, 256, 0, stream>>>(h_buf, asl[1], adl[1], a_s, a_d, N);
  agg_kernel<<<N, 64, 0, stream>>>(h_buf, a_s, a_d, off, csr, bl[1], x_buf);
  // layer 3
  gemm_kernel<<<ggrid, 256, 0, stream>>>(x_buf, Wl[2], h_buf, N);
  attn_kernel<<<ab, 256, 0, stream>>>(h_buf, asl[2], adl[2], a_s, a_d, N);
  agg_kernel<<<N, 64, 0, stream>>>(h_buf, a_s, a_d, off, csr, bl[2], out);
}

// Round 3
// 372.691 us; speedup vs baseline: 1.0240x; 1.0240x over previous
//
#include <hip/hip_runtime.h>
#include <hip/hip_bf16.h>

// All float tensors fp32; edge_index int32.

// ---------------- CSR build (graph identical across the 3 layers) ----------------

__global__ void count_kernel(const int* __restrict__ ei, int E, int N, int* __restrict__ cnt) {
  int t = blockIdx.x * blockDim.x + threadIdx.x;
  if (t >= E + N) return;
  int dst = (t < E) ? ei[E + t] : (t - E);
  atomicAdd(&cnt[dst], 1);
}

// single block of 1024 threads; handles N <= 16384.
__global__ void scan_kernel(int* __restrict__ cnt_cursor, int* __restrict__ off, int N) {
  __shared__ int sdata[1024];
  const int CH = 16;
  int tid = threadIdx.x;
  int base = tid * CH;
  int lc[CH];
  int lsum = 0;
#pragma unroll
  for (int j = 0; j < CH; j++) {
    int idx = base + j;
    int v = (idx < N) ? cnt_cursor[idx] : 0;
    lc[j] = v;
    lsum += v;
  }
  sdata[tid] = lsum;
  __syncthreads();
  for (int o = 1; o < 1024; o <<= 1) {
    int v = (tid >= o) ? sdata[tid - o] : 0;
    __syncthreads();
    sdata[tid] += v;
    __syncthreads();
  }
  int run = sdata[tid] - lsum;
#pragma unroll
  for (int j = 0; j < CH; j++) {
    int idx = base + j;
    if (idx < N) { off[idx] = run; cnt_cursor[idx] = run; }
    run += lc[j];
  }
  if (tid == 1023) off[N] = sdata[1023];
}

__global__ void fill_kernel(const int* __restrict__ ei, int E, int N,
                            int* __restrict__ cursor, int* __restrict__ csr,
                            int* __restrict__ csr_dst) {
  int t = blockIdx.x * blockDim.x + threadIdx.x;
  if (t >= E + N) return;
  int src, dst;
  if (t < E) { src = ei[t]; dst = ei[E + t]; }
  else       { src = t - E; dst = t - E; }
  int pos = atomicAdd(&cursor[dst], 1);
  csr[pos] = src;
  csr_dst[pos] = dst;
}

// ---------------- fused GEMM + attention dots ----------------
// H[M,256] = X[M,256] @ W[256,256]; blockIdx.y = head (64-col block).
// 64x64 tile, 256 threads, 4x4 micro-tile, A staged transposed (k-major,
// stride 68 words -> 2-way LDS aliasing = free) so fragments load as b128.
// Epilogue: a_s/a_d[row][head] = dot(h_row_head, att) via 16-lane shfl reduce.

__global__ void gemm_attn_kernel(const float* __restrict__ X, const float* __restrict__ W,
                                 const float* __restrict__ att_s, const float* __restrict__ att_d,
                                 float* __restrict__ H, float* __restrict__ a_s,
                                 float* __restrict__ a_d, int M) {
  const int K = 256, NN = 256, LD = 68;
  __shared__ float As[16 * LD];  // As[k][m]
  __shared__ float Bs[16 * LD];  // Bs[k][n]
  int tid = threadIdx.x;            // 256
  int tx = tid & 15, ty = tid >> 4; // col group / row group
  int m0 = blockIdx.x * 64;
  int hd = blockIdx.y;
  int n0 = hd * 64;

  int lm = tid >> 2;             // 0..63: A row
  int lk = (tid & 3) * 4;        // 0,4,8,12: A k-chunk
  int bk = tid >> 4;             // 0..15: B k-row
  int bn = (tid & 15) * 4;       // B col chunk

  float c[4][4] = {};

  for (int k0 = 0; k0 < K; k0 += 16) {
    int gm = m0 + lm;
    float4 v = make_float4(0.f, 0.f, 0.f, 0.f);
    if (gm < M) v = *(const float4*)&X[gm * K + k0 + lk];
    As[(lk + 0) * LD + lm] = v.x;
    As[(lk + 1) * LD + lm] = v.y;
    As[(lk + 2) * LD + lm] = v.z;
    As[(lk + 3) * LD + lm] = v.w;
    *(float4*)&Bs[bk * LD + bn] = *(const float4*)&W[(k0 + bk) * NN + n0 + bn];
    __syncthreads();
#pragma unroll
    for (int kk = 0; kk < 16; kk++) {
      float4 a4 = *(const float4*)&As[kk * LD + ty * 4];
      float4 b4 = *(const float4*)&Bs[kk * LD + tx * 4];
      const float a[4] = {a4.x, a4.y, a4.z, a4.w};
      const float b[4] = {b4.x, b4.y, b4.z, b4.w};
#pragma unroll
      for (int i = 0; i < 4; i++)
#pragma unroll
        for (int j = 0; j < 4; j++) c[i][j] += a[i] * b[j];
    }
    __syncthreads();
  }

  const float4 s4 = *(const float4*)&att_s[hd * 64 + tx * 4];
  const float4 d4 = *(const float4*)&att_d[hd * 64 + tx * 4];
#pragma unroll
  for (int i = 0; i < 4; i++) {
    int gm = m0 + ty * 4 + i;
    float4 row = make_float4(c[i][0], c[i][1], c[i][2], c[i][3]);
    float ps = c[i][0] * s4.x + c[i][1] * s4.y + c[i][2] * s4.z + c[i][3] * s4.w;
    float pd = c[i][0] * d4.x + c[i][1] * d4.y + c[i][2] * d4.z + c[i][3] * d4.w;
#pragma unroll
    for (int s = 1; s < 16; s <<= 1) {
      ps += __shfl_xor(ps, s, 64);
      pd += __shfl_xor(pd, s, 64);
    }
    if (gm < M) {
      *(float4*)&H[gm * 256 + n0 + tx * 4] = row;
      if (tx == 0) { a_s[gm * 4 + hd] = ps; a_d[gm * 4 + hd] = pd; }
    }
  }
}

// ---------------- per-edge raw attention logits (CSR order) ----------------

__global__ void edge_e_kernel(const int* __restrict__ csr, const int* __restrict__ csr_dst,
                              const float* __restrict__ a_s, const float* __restrict__ a_d,
                              float* __restrict__ ea, int Etot) {
  int t = blockIdx.x * blockDim.x + threadIdx.x;
  if (t >= Etot) return;
  int s = csr[t], d = csr_dst[t];
  float4 as4 = *(const float4*)&a_s[s * 4];
  float4 ad4 = *(const float4*)&a_d[d * 4];
  float4 e;
  e.x = as4.x + ad4.x; e.x = (e.x > 0.f) ? e.x : 0.2f * e.x;
  e.y = as4.y + ad4.y; e.y = (e.y > 0.f) ? e.y : 0.2f * e.y;
  e.z = as4.z + ad4.z; e.z = (e.z > 0.f) ? e.z : 0.2f * e.z;
  e.w = as4.w + ad4.w; e.w = (e.w > 0.f) ? e.w : 0.2f * e.w;
  *(float4*)&ea[t * 4] = e;
}

// ---------------- segment softmax in place: ea(e) -> ea(alpha) ----------------
// one wave per dst node; sequential coalesced float4 sweeps over its segment.

__global__ void softmax_kernel(const int* __restrict__ off, float* __restrict__ ea) {
  int n = blockIdx.x;
  int lane = threadIdx.x;  // 64
  int o0 = off[n], o1 = off[n + 1];
  int deg = o1 - o0;

  float mx[4] = {-1e30f, -1e30f, -1e30f, -1e30f};
  for (int i = lane; i < deg; i += 64) {
    float4 e = *(const float4*)&ea[(o0 + i) * 4];
    mx[0] = fmaxf(mx[0], e.x); mx[1] = fmaxf(mx[1], e.y);
    mx[2] = fmaxf(mx[2], e.z); mx[3] = fmaxf(mx[3], e.w);
  }
#pragma unroll
  for (int h = 0; h < 4; h++)
#pragma unroll
    for (int s = 1; s < 64; s <<= 1) mx[h] = fmaxf(mx[h], __shfl_xor(mx[h], s, 64));

  float sm[4] = {0.f, 0.f, 0.f, 0.f};
  for (int i = lane; i < deg; i += 64) {
    float4 e = *(const float4*)&ea[(o0 + i) * 4];
    float4 p;
    p.x = __expf(e.x - mx[0]); p.y = __expf(e.y - mx[1]);
    p.z = __expf(e.z - mx[2]); p.w = __expf(e.w - mx[3]);
    sm[0] += p.x; sm[1] += p.y; sm[2] += p.z; sm[3] += p.w;
    *(float4*)&ea[(o0 + i) * 4] = p;
  }
#pragma unroll
  for (int h = 0; h < 4; h++)
#pragma unroll
    for (int s = 1; s < 64; s <<= 1) sm[h] += __shfl_xor(sm[h], s, 64);

  float4 inv;
  inv.x = 1.f / (sm[0] + 1e-16f); inv.y = 1.f / (sm[1] + 1e-16f);
  inv.z = 1.f / (sm[2] + 1e-16f); inv.w = 1.f / (sm[3] + 1e-16f);
  for (int i = lane; i < deg; i += 64) {
    float4 p = *(const float4*)&ea[(o0 + i) * 4];
    p.x *= inv.x; p.y *= inv.y; p.z *= inv.z; p.w *= inv.w;
    *(float4*)&ea[(o0 + i) * 4] = p;
  }
}

// ---------------- gather-aggregate + bias + ELU ----------------
// one wave per dst node; lane owns 4 channels (float4) -> one dwordx4/edge/wave.

__global__ void agg_kernel(const float* __restrict__ H, const float* __restrict__ ea,
                           const int* __restrict__ off, const int* __restrict__ csr,
                           const float* __restrict__ bias, float* __restrict__ Out) {
  int n = blockIdx.x;
  int lane = threadIdx.x;  // 64
  int o0 = off[n], o1 = off[n + 1];
  int deg = o1 - o0;
  int head = lane >> 4;    // channels lane*4..lane*4+3 all in this head

  __shared__ int ssrc[64];
  __shared__ float4 sal[64];

  float4 acc = make_float4(0.f, 0.f, 0.f, 0.f);
  for (int base = 0; base < deg; base += 64) {
    int cnt = min(64, deg - base);
    if (lane < cnt) {
      ssrc[lane] = csr[o0 + base + lane];
      sal[lane] = *(const float4*)&ea[(o0 + base + lane) * 4];
    }
    __syncthreads();
    for (int i = 0; i < cnt; i++) {
      const float4 h4 = *(const float4*)&H[ssrc[i] * 256 + lane * 4];
      const float w = ((const float*)&sal[i])[head];
      acc.x += w * h4.x; acc.y += w * h4.y;
      acc.z += w * h4.z; acc.w += w * h4.w;
    }
    __syncthreads();
  }

  const float4 b4 = *(const float4*)&bias[lane * 4];
  float4 v;
  v.x = acc.x + b4.x; v.y = acc.y + b4.y; v.z = acc.z + b4.z; v.w = acc.w + b4.w;
  v.x = (v.x > 0.f) ? v.x : expm1f(v.x);
  v.y = (v.y > 0.f) ? v.y : expm1f(v.y);
  v.z = (v.z > 0.f) ? v.z : expm1f(v.z);
  v.w = (v.w > 0.f) ? v.w : expm1f(v.w);
  *(float4*)&Out[n * 256 + lane * 4] = v;
}

// ---------------- launch ----------------

extern "C" void kernel_launch(void* const* d_in, const int* in_sizes, int n_in,
                              void* d_out, int out_size, void* d_ws, size_t ws_size,
                              hipStream_t stream) {
  const int N = in_sizes[0] / 256;   // 10000
  const int E = in_sizes[1] / 2;     // 320000
  const int Etot = E + N;

  const float* x  = (const float*)d_in[0];
  const int*   ei = (const int*)d_in[1];
  const float* Wl[3]  = {(const float*)d_in[2], (const float*)d_in[6], (const float*)d_in[10]};
  const float* asl[3] = {(const float*)d_in[3], (const float*)d_in[7], (const float*)d_in[11]};
  const float* adl[3] = {(const float*)d_in[4], (const float*)d_in[8], (const float*)d_in[12]};
  const float* bl[3]  = {(const float*)d_in[5], (const float*)d_in[9], (const float*)d_in[13]};
  float* out = (float*)d_out;

  char* p = (char*)d_ws;
  auto carve = [&](size_t bytes) {
    char* r = p;
    p += (bytes + 255) & ~size_t(255);
    return r;
  };
  int*   off     = (int*)carve(sizeof(int) * (N + 1));
  int*   cursor  = (int*)carve(sizeof(int) * N);
  int*   csr     = (int*)carve(sizeof(int) * Etot);
  int*   csr_dst = (int*)carve(sizeof(int) * Etot);
  float* a_s     = (float*)carve(sizeof(float) * N * 4);
  float* a_d     = (float*)carve(sizeof(float) * N * 4);
  float* ea      = (float*)carve(sizeof(float) * Etot * 4);
  float* h_buf   = (float*)carve(sizeof(float) * N * 256);
  float* x_buf   = (float*)carve(sizeof(float) * N * 256);
  (void)ws_size; (void)n_in; (void)out_size;

  hipMemsetAsync(cursor, 0, sizeof(int) * N, stream);
  int eb = (Etot + 255) / 256;
  count_kernel<<<eb, 256, 0, stream>>>(ei, E, N, cursor);
  scan_kernel<<<1, 1024, 0, stream>>>(cursor, off, N);
  fill_kernel<<<eb, 256, 0, stream>>>(ei, E, N, cursor, csr, csr_dst);

  dim3 ggrid((N + 63) / 64, 4);

  const float* xin = x;
  for (int L = 0; L < 3; L++) {
    float* dst = (L == 2) ? out : x_buf;
    gemm_attn_kernel<<<ggrid, 256, 0, stream>>>(xin, Wl[L], asl[L], adl[L],
                                                h_buf, a_s, a_d, N);
    edge_e_kernel<<<eb, 256, 0, stream>>>(csr, csr_dst, a_s, a_d, ea, Etot);
    softmax_kernel<<<N, 64, 0, stream>>>(off, ea);
    agg_kernel<<<N, 64, 0, stream>>>(h_buf, ea, off, csr, bl[L], dst);
    xin = x_buf;
  }
}

// Round 4
// 341.263 us; speedup vs baseline: 1.1183x; 1.0921x over previous
//
#include <hip/hip_runtime.h>
#include <hip/hip_bf16.h>

// All float tensors fp32; edge_index int32.

// ---------------- CSR build (graph identical across the 3 layers) ----------------

__global__ void count_kernel(const int* __restrict__ ei, int E, int N, int* __restrict__ cnt) {
  int t = blockIdx.x * blockDim.x + threadIdx.x;
  if (t >= E + N) return;
  int dst = (t < E) ? ei[E + t] : (t - E);
  atomicAdd(&cnt[dst], 1);
}

// single block of 1024 threads; handles N <= 16384.
__global__ void scan_kernel(int* __restrict__ cnt_cursor, int* __restrict__ off, int N) {
  __shared__ int sdata[1024];
  const int CH = 16;
  int tid = threadIdx.x;
  int base = tid * CH;
  int lc[CH];
  int lsum = 0;
#pragma unroll
  for (int j = 0; j < CH; j++) {
    int idx = base + j;
    int v = (idx < N) ? cnt_cursor[idx] : 0;
    lc[j] = v;
    lsum += v;
  }
  sdata[tid] = lsum;
  __syncthreads();
  for (int o = 1; o < 1024; o <<= 1) {
    int v = (tid >= o) ? sdata[tid - o] : 0;
    __syncthreads();
    sdata[tid] += v;
    __syncthreads();
  }
  int run = sdata[tid] - lsum;
#pragma unroll
  for (int j = 0; j < CH; j++) {
    int idx = base + j;
    if (idx < N) { off[idx] = run; cnt_cursor[idx] = run; }
    run += lc[j];
  }
  if (tid == 1023) off[N] = sdata[1023];
}

__global__ void fill_kernel(const int* __restrict__ ei, int E, int N,
                            int* __restrict__ cursor, int* __restrict__ csr) {
  int t = blockIdx.x * blockDim.x + threadIdx.x;
  if (t >= E + N) return;
  int src, dst;
  if (t < E) { src = ei[t]; dst = ei[E + t]; }
  else       { src = t - E; dst = t - E; }
  int pos = atomicAdd(&cursor[dst], 1);
  csr[pos] = src;
}

// ---------------- fused GEMM + attention dots ----------------
// H[M,256] = X[M,256] @ W[256,256]; blockIdx.y = head (64-col block).
// 64x64 tile, 256 threads, 4x4 micro-tile, A staged transposed (k-major,
// stride 68 words -> 2-way LDS aliasing = free) so fragments load as b128.
// Epilogue: a_s/a_d[row][head] = dot(h_row_head, att) via 16-lane shfl reduce.

__global__ void gemm_attn_kernel(const float* __restrict__ X, const float* __restrict__ W,
                                 const float* __restrict__ att_s, const float* __restrict__ att_d,
                                 float* __restrict__ H, float* __restrict__ a_s,
                                 float* __restrict__ a_d, int M) {
  const int K = 256, NN = 256, LD = 68;
  __shared__ float As[16 * LD];  // As[k][m]
  __shared__ float Bs[16 * LD];  // Bs[k][n]
  int tid = threadIdx.x;            // 256
  int tx = tid & 15, ty = tid >> 4; // col group / row group
  int m0 = blockIdx.x * 64;
  int hd = blockIdx.y;
  int n0 = hd * 64;

  int lm = tid >> 2;             // 0..63: A row
  int lk = (tid & 3) * 4;        // 0,4,8,12: A k-chunk
  int bk = tid >> 4;             // 0..15: B k-row
  int bn = (tid & 15) * 4;       // B col chunk

  float c[4][4] = {};

  for (int k0 = 0; k0 < K; k0 += 16) {
    int gm = m0 + lm;
    float4 v = make_float4(0.f, 0.f, 0.f, 0.f);
    if (gm < M) v = *(const float4*)&X[gm * K + k0 + lk];
    As[(lk + 0) * LD + lm] = v.x;
    As[(lk + 1) * LD + lm] = v.y;
    As[(lk + 2) * LD + lm] = v.z;
    As[(lk + 3) * LD + lm] = v.w;
    *(float4*)&Bs[bk * LD + bn] = *(const float4*)&W[(k0 + bk) * NN + n0 + bn];
    __syncthreads();
#pragma unroll
    for (int kk = 0; kk < 16; kk++) {
      float4 a4 = *(const float4*)&As[kk * LD + ty * 4];
      float4 b4 = *(const float4*)&Bs[kk * LD + tx * 4];
      const float a[4] = {a4.x, a4.y, a4.z, a4.w};
      const float b[4] = {b4.x, b4.y, b4.z, b4.w};
#pragma unroll
      for (int i = 0; i < 4; i++)
#pragma unroll
        for (int j = 0; j < 4; j++) c[i][j] += a[i] * b[j];
    }
    __syncthreads();
  }

  const float4 s4 = *(const float4*)&att_s[hd * 64 + tx * 4];
  const float4 d4 = *(const float4*)&att_d[hd * 64 + tx * 4];
#pragma unroll
  for (int i = 0; i < 4; i++) {
    int gm = m0 + ty * 4 + i;
    float4 row = make_float4(c[i][0], c[i][1], c[i][2], c[i][3]);
    float ps = c[i][0] * s4.x + c[i][1] * s4.y + c[i][2] * s4.z + c[i][3] * s4.w;
    float pd = c[i][0] * d4.x + c[i][1] * d4.y + c[i][2] * d4.z + c[i][3] * d4.w;
#pragma unroll
    for (int s = 1; s < 16; s <<= 1) {
      ps += __shfl_xor(ps, s, 64);
      pd += __shfl_xor(pd, s, 64);
    }
    if (gm < M) {
      *(float4*)&H[gm * 256 + n0 + tx * 4] = row;
      if (tx == 0) { a_s[gm * 4 + hd] = ps; a_d[gm * 4 + hd] = pd; }
    }
  }
}

// ---------------- fused edge pipeline: online segment-softmax + gather + bias + ELU ----
// block = 256 threads = 4 waves; wave w owns node n = blockIdx*4 + w.
// lane owns 4 channels (float4 of H row); head = lane>>4.
// Per edge: e = leaky(a_s[src][head] + a_d[n][head]); online softmax (m,s) kept
// redundantly per lane (identical within a head group -> no shuffles, no LDS,
// no barriers). acc rescaled by exp(m_old - m_new). Final: acc/(s+1e-16)+b, ELU.

__device__ __forceinline__ void agg_step(float e, const float4 h, float& m, float& s,
                                         float4& acc) {
  e = (e > 0.f) ? e : 0.2f * e;
  float mn = fmaxf(m, e);
  float c = __expf(m - mn);
  float p = __expf(e - mn);
  s = s * c + p;
  acc.x = acc.x * c + p * h.x;
  acc.y = acc.y * c + p * h.y;
  acc.z = acc.z * c + p * h.z;
  acc.w = acc.w * c + p * h.w;
  m = mn;
}

__global__ void __launch_bounds__(256, 8)
agg_fused_kernel(const float* __restrict__ H, const float* __restrict__ a_s,
                 const float* __restrict__ a_d, const int* __restrict__ off,
                 const int* __restrict__ csr, const float* __restrict__ bias,
                 float* __restrict__ Out, int N) {
  int wave = threadIdx.x >> 6;
  int lane = threadIdx.x & 63;
  int n = blockIdx.x * 4 + wave;
  if (n >= N) return;
  int head = lane >> 4;
  int ch4 = lane * 4;

  int o0 = off[n], o1 = off[n + 1];
  float ad = a_d[n * 4 + head];

  float m = -1e30f, s = 0.f;
  float4 acc = make_float4(0.f, 0.f, 0.f, 0.f);

  int i = o0;
  for (; i + 4 <= o1; i += 4) {
    int s0 = csr[i], s1 = csr[i + 1], s2 = csr[i + 2], s3 = csr[i + 3];
    float e0 = a_s[s0 * 4 + head] + ad;
    float e1 = a_s[s1 * 4 + head] + ad;
    float e2 = a_s[s2 * 4 + head] + ad;
    float e3 = a_s[s3 * 4 + head] + ad;
    const float4 h0 = *(const float4*)&H[(s0 << 8) + ch4];
    const float4 h1 = *(const float4*)&H[(s1 << 8) + ch4];
    const float4 h2 = *(const float4*)&H[(s2 << 8) + ch4];
    const float4 h3 = *(const float4*)&H[(s3 << 8) + ch4];
    agg_step(e0, h0, m, s, acc);
    agg_step(e1, h1, m, s, acc);
    agg_step(e2, h2, m, s, acc);
    agg_step(e3, h3, m, s, acc);
  }
  for (; i < o1; i++) {
    int s0 = csr[i];
    float e0 = a_s[s0 * 4 + head] + ad;
    const float4 h0 = *(const float4*)&H[(s0 << 8) + ch4];
    agg_step(e0, h0, m, s, acc);
  }

  float inv = 1.f / (s + 1e-16f);
  const float4 b4 = *(const float4*)&bias[ch4];
  float4 v;
  v.x = acc.x * inv + b4.x;
  v.y = acc.y * inv + b4.y;
  v.z = acc.z * inv + b4.z;
  v.w = acc.w * inv + b4.w;
  v.x = (v.x > 0.f) ? v.x : expm1f(v.x);
  v.y = (v.y > 0.f) ? v.y : expm1f(v.y);
  v.z = (v.z > 0.f) ? v.z : expm1f(v.z);
  v.w = (v.w > 0.f) ? v.w : expm1f(v.w);
  *(float4*)&Out[n * 256 + ch4] = v;
}

// ---------------- launch ----------------

extern "C" void kernel_launch(void* const* d_in, const int* in_sizes, int n_in,
                              void* d_out, int out_size, void* d_ws, size_t ws_size,
                              hipStream_t stream) {
  const int N = in_sizes[0] / 256;   // 10000
  const int E = in_sizes[1] / 2;     // 320000
  const int Etot = E + N;

  const float* x  = (const float*)d_in[0];
  const int*   ei = (const int*)d_in[1];
  const float* Wl[3]  = {(const float*)d_in[2], (const float*)d_in[6], (const float*)d_in[10]};
  const float* asl[3] = {(const float*)d_in[3], (const float*)d_in[7], (const float*)d_in[11]};
  const float* adl[3] = {(const float*)d_in[4], (const float*)d_in[8], (const float*)d_in[12]};
  const float* bl[3]  = {(const float*)d_in[5], (const float*)d_in[9], (const float*)d_in[13]};
  float* out = (float*)d_out;

  char* p = (char*)d_ws;
  auto carve = [&](size_t bytes) {
    char* r = p;
    p += (bytes + 255) & ~size_t(255);
    return r;
  };
  int*   off     = (int*)carve(sizeof(int) * (N + 1));
  int*   cursor  = (int*)carve(sizeof(int) * N);
  int*   csr     = (int*)carve(sizeof(int) * Etot);
  float* a_s     = (float*)carve(sizeof(float) * N * 4);
  float* a_d     = (float*)carve(sizeof(float) * N * 4);
  float* h_buf   = (float*)carve(sizeof(float) * N * 256);
  float* x_buf   = (float*)carve(sizeof(float) * N * 256);
  (void)ws_size; (void)n_in; (void)out_size;

  hipMemsetAsync(cursor, 0, sizeof(int) * N, stream);
  int eb = (Etot + 255) / 256;
  count_kernel<<<eb, 256, 0, stream>>>(ei, E, N, cursor);
  scan_kernel<<<1, 1024, 0, stream>>>(cursor, off, N);
  fill_kernel<<<eb, 256, 0, stream>>>(ei, E, N, cursor, csr);

  dim3 ggrid((N + 63) / 64, 4);
  int ab = (N + 3) / 4;

  const float* xin = x;
  for (int L = 0; L < 3; L++) {
    float* dst = (L == 2) ? out : x_buf;
    gemm_attn_kernel<<<ggrid, 256, 0, stream>>>(xin, Wl[L], asl[L], adl[L],
                                                h_buf, a_s, a_d, N);
    agg_fused_kernel<<<ab, 256, 0, stream>>>(h_buf, a_s, a_d, off, csr, bl[L], dst, N);
    xin = x_buf;
  }
}

// Round 5
// 267.647 us; speedup vs baseline: 1.4259x; 1.2751x over previous
//
#include <hip/hip_runtime.h>
#include <hip/hip_bf16.h>

typedef __hip_bfloat16 bf16;
typedef __bf16 bf16x8 __attribute__((ext_vector_type(8)));
typedef float f32x4 __attribute__((ext_vector_type(4)));

__device__ __forceinline__ float bits2f(unsigned short u) {
  union { unsigned int i; float f; } c;
  c.i = ((unsigned int)u) << 16;
  return c.f;
}

// ---------------- CSR build (graph identical across the 3 layers) ----------------

__global__ void count_kernel(const int* __restrict__ ei, int E, int N, int* __restrict__ cnt) {
  int t = blockIdx.x * blockDim.x + threadIdx.x;
  if (t >= E + N) return;
  int dst = (t < E) ? ei[E + t] : (t - E);
  atomicAdd(&cnt[dst], 1);
}

__global__ void scan_kernel(int* __restrict__ cnt_cursor, int* __restrict__ off, int N) {
  __shared__ int sdata[1024];
  const int CH = 16;
  int tid = threadIdx.x;
  int base = tid * CH;
  int lc[CH];
  int lsum = 0;
#pragma unroll
  for (int j = 0; j < CH; j++) {
    int idx = base + j;
    int v = (idx < N) ? cnt_cursor[idx] : 0;
    lc[j] = v;
    lsum += v;
  }
  sdata[tid] = lsum;
  __syncthreads();
  for (int o = 1; o < 1024; o <<= 1) {
    int v = (tid >= o) ? sdata[tid - o] : 0;
    __syncthreads();
    sdata[tid] += v;
    __syncthreads();
  }
  int run = sdata[tid] - lsum;
#pragma unroll
  for (int j = 0; j < CH; j++) {
    int idx = base + j;
    if (idx < N) { off[idx] = run; cnt_cursor[idx] = run; }
    run += lc[j];
  }
  if (tid == 1023) off[N] = sdata[1023];
}

__global__ void fill_kernel(const int* __restrict__ ei, int E, int N,
                            int* __restrict__ cursor, int* __restrict__ csr) {
  int t = blockIdx.x * blockDim.x + threadIdx.x;
  if (t >= E + N) return;
  int src, dst;
  if (t < E) { src = ei[t]; dst = ei[E + t]; }
  else       { src = t - E; dst = t - E; }
  int pos = atomicAdd(&cursor[dst], 1);
  csr[pos] = src;
}

// ---------------- weight transpose + cast: Wt[n][k] = bf16(W[k][n]), 3 layers ----------

__global__ void wt_kernel(const float* __restrict__ W0, const float* __restrict__ W1,
                          const float* __restrict__ W2, bf16* __restrict__ Wt) {
  const float* W = (blockIdx.z == 0) ? W0 : (blockIdx.z == 1) ? W1 : W2;
  bf16* T = Wt + (size_t)blockIdx.z * 65536;
  __shared__ float tile[16][17];
  int k0 = blockIdx.y * 16, n0 = blockIdx.x * 16;
  int tx = threadIdx.x & 15, ty = threadIdx.x >> 4;  // 256 threads
  tile[ty][tx] = W[(k0 + ty) * 256 + n0 + tx];
  __syncthreads();
  T[(n0 + ty) * 256 + k0 + tx] = __float2bfloat16(tile[tx][ty]);
}

// ---------------- MFMA GEMM + fused attention dots ----------------
// H[M,256] = X[M,256] @ W[256,256] (bf16 in, fp32 acc, bf16 out).
// grid (ceil(M/64), 4 heads); block 256 = 4 waves; wave w owns 16-row strip.
// LDS k-major tiles, BK=32, +8 bf16 pad. Frag layouts (m89/m120 verified):
//   A[m=lane&15][k=quad*8+j], B[n=lane&15][k=quad*8+j], D[col=lane&15][row=quad*4+reg].
// Epilogue: H store (bf16) + a_s/a_d dots via 16-lane shfl reduce.

template <bool FP32IN>
__global__ void __launch_bounds__(256)
gemm_mfma_kernel(const void* __restrict__ Xv, const bf16* __restrict__ Wt,
                 const float* __restrict__ att_s, const float* __restrict__ att_d,
                 bf16* __restrict__ H, float* __restrict__ a_s, float* __restrict__ a_d,
                 int M) {
  const int LDK = 40;  // 32 + 8 pad (bf16 units); row stride 80 B (16B-aligned)
  __shared__ bf16 As[64 * LDK];
  __shared__ bf16 Bs[64 * LDK];
  int tid = threadIdx.x;
  int wave = tid >> 6, lane = tid & 63;
  int quad = lane >> 4, l16 = lane & 15;
  int m0 = blockIdx.x * 64;
  int hd = blockIdx.y;
  int n0 = hd * 64;

  int srow = tid >> 2;          // 0..63 staging row
  int skoff = (tid & 3) * 8;    // bf16 offset within 32-k slice

  const float* Xf = (const float*)Xv;
  const bf16*  Xb = (const bf16*)Xv;

  f32x4 acc[4] = {{0.f, 0.f, 0.f, 0.f}, {0.f, 0.f, 0.f, 0.f},
                  {0.f, 0.f, 0.f, 0.f}, {0.f, 0.f, 0.f, 0.f}};

  for (int k0 = 0; k0 < 256; k0 += 32) {
    int gm = m0 + srow;
    if (FP32IN) {
      float4 u0 = make_float4(0.f, 0.f, 0.f, 0.f), u1 = u0;
      if (gm < M) {
        u0 = *(const float4*)&Xf[gm * 256 + k0 + skoff];
        u1 = *(const float4*)&Xf[gm * 256 + k0 + skoff + 4];
      }
      union { bf16 h[8]; uint4 u; } pk;
      pk.h[0] = __float2bfloat16(u0.x); pk.h[1] = __float2bfloat16(u0.y);
      pk.h[2] = __float2bfloat16(u0.z); pk.h[3] = __float2bfloat16(u0.w);
      pk.h[4] = __float2bfloat16(u1.x); pk.h[5] = __float2bfloat16(u1.y);
      pk.h[6] = __float2bfloat16(u1.z); pk.h[7] = __float2bfloat16(u1.w);
      *(uint4*)&As[srow * LDK + skoff] = pk.u;
    } else {
      uint4 v = make_uint4(0u, 0u, 0u, 0u);
      if (gm < M) v = *(const uint4*)&Xb[gm * 256 + k0 + skoff];
      *(uint4*)&As[srow * LDK + skoff] = v;
    }
    *(uint4*)&Bs[srow * LDK + skoff] = *(const uint4*)&Wt[(n0 + srow) * 256 + k0 + skoff];
    __syncthreads();

    bf16x8 af = *(const bf16x8*)&As[(wave * 16 + l16) * LDK + quad * 8];
#pragma unroll
    for (int t = 0; t < 4; t++) {
      bf16x8 bfr = *(const bf16x8*)&Bs[(t * 16 + l16) * LDK + quad * 8];
      acc[t] = __builtin_amdgcn_mfma_f32_16x16x32_bf16(af, bfr, acc[t], 0, 0, 0);
    }
    __syncthreads();
  }

  // epilogue: H (bf16) + attention dots
  float ps[4] = {0.f, 0.f, 0.f, 0.f}, pd[4] = {0.f, 0.f, 0.f, 0.f};
#pragma unroll
  for (int t = 0; t < 4; t++) {
    float sa = att_s[hd * 64 + t * 16 + l16];
    float da = att_d[hd * 64 + t * 16 + l16];
#pragma unroll
    for (int j = 0; j < 4; j++) {
      int gm = m0 + wave * 16 + quad * 4 + j;
      float v = acc[t][j];
      if (gm < M) H[gm * 256 + n0 + t * 16 + l16] = __float2bfloat16(v);
      ps[j] += v * sa;
      pd[j] += v * da;
    }
  }
#pragma unroll
  for (int j = 0; j < 4; j++) {
#pragma unroll
    for (int s = 1; s < 16; s <<= 1) {
      ps[j] += __shfl_xor(ps[j], s, 64);
      pd[j] += __shfl_xor(pd[j], s, 64);
    }
    int gm = m0 + wave * 16 + quad * 4 + j;
    if (l16 == 0 && gm < M) {
      a_s[gm * 4 + hd] = ps[j];
      a_d[gm * 4 + hd] = pd[j];
    }
  }
}

// ---------------- fused online segment-softmax + gather + bias + ELU ----------------
// block = 4 waves; wave owns node n. lane owns 4 channels (8 B bf16 gather).
// m/s state redundant per lane within head group -> no shuffles/LDS/barriers.

__device__ __forceinline__ void agg_step(float e, const float4 h, float& m, float& s,
                                         float4& acc) {
  e = (e > 0.f) ? e : 0.2f * e;
  float mn = fmaxf(m, e);
  float c = __expf(m - mn);
  float p = __expf(e - mn);
  s = s * c + p;
  acc.x = acc.x * c + p * h.x;
  acc.y = acc.y * c + p * h.y;
  acc.z = acc.z * c + p * h.z;
  acc.w = acc.w * c + p * h.w;
  m = mn;
}

__device__ __forceinline__ float4 ld_h(const bf16* __restrict__ H, int s, int ch4) {
  ushort4 u = *(const ushort4*)((const unsigned short*)H + (s << 8) + ch4);
  return make_float4(bits2f(u.x), bits2f(u.y), bits2f(u.z), bits2f(u.w));
}

template <bool FINAL>
__global__ void __launch_bounds__(256, 8)
agg_fused_kernel(const bf16* __restrict__ H, const float* __restrict__ a_s,
                 const float* __restrict__ a_d, const int* __restrict__ off,
                 const int* __restrict__ csr, const float* __restrict__ bias,
                 bf16* __restrict__ OutB, float* __restrict__ OutF, int N) {
  int wave = threadIdx.x >> 6;
  int lane = threadIdx.x & 63;
  int n = blockIdx.x * 4 + wave;
  if (n >= N) return;
  int head = lane >> 4;
  int ch4 = lane * 4;

  int o0 = off[n], o1 = off[n + 1];
  float ad = a_d[n * 4 + head];

  float m = -1e30f, s = 0.f;
  float4 acc = make_float4(0.f, 0.f, 0.f, 0.f);

  int i = o0;
  for (; i + 4 <= o1; i += 4) {
    int s0 = csr[i], s1 = csr[i + 1], s2 = csr[i + 2], s3 = csr[i + 3];
    float e0 = a_s[s0 * 4 + head] + ad;
    float e1 = a_s[s1 * 4 + head] + ad;
    float e2 = a_s[s2 * 4 + head] + ad;
    float e3 = a_s[s3 * 4 + head] + ad;
    const float4 h0 = ld_h(H, s0, ch4);
    const float4 h1 = ld_h(H, s1, ch4);
    const float4 h2 = ld_h(H, s2, ch4);
    const float4 h3 = ld_h(H, s3, ch4);
    agg_step(e0, h0, m, s, acc);
    agg_step(e1, h1, m, s, acc);
    agg_step(e2, h2, m, s, acc);
    agg_step(e3, h3, m, s, acc);
  }
  for (; i < o1; i++) {
    int s0 = csr[i];
    float e0 = a_s[s0 * 4 + head] + ad;
    const float4 h0 = ld_h(H, s0, ch4);
    agg_step(e0, h0, m, s, acc);
  }

  float inv = 1.f / (s + 1e-16f);
  const float4 b4 = *(const float4*)&bias[ch4];
  float4 v;
  v.x = acc.x * inv + b4.x;
  v.y = acc.y * inv + b4.y;
  v.z = acc.z * inv + b4.z;
  v.w = acc.w * inv + b4.w;
  v.x = (v.x > 0.f) ? v.x : expm1f(v.x);
  v.y = (v.y > 0.f) ? v.y : expm1f(v.y);
  v.z = (v.z > 0.f) ? v.z : expm1f(v.z);
  v.w = (v.w > 0.f) ? v.w : expm1f(v.w);
  if (FINAL) {
    *(float4*)&OutF[n * 256 + ch4] = v;
  } else {
    union { bf16 h[4]; ushort4 u; } pk;
    pk.h[0] = __float2bfloat16(v.x); pk.h[1] = __float2bfloat16(v.y);
    pk.h[2] = __float2bfloat16(v.z); pk.h[3] = __float2bfloat16(v.w);
    *(ushort4*)((unsigned short*)OutB + n * 256 + ch4) = pk.u;
  }
}

// ---------------- launch ----------------

extern "C" void kernel_launch(void* const* d_in, const int* in_sizes, int n_in,
                              void* d_out, int out_size, void* d_ws, size_t ws_size,
                              hipStream_t stream) {
  const int N = in_sizes[0] / 256;   // 10000
  const int E = in_sizes[1] / 2;     // 320000
  const int Etot = E + N;

  const float* x  = (const float*)d_in[0];
  const int*   ei = (const int*)d_in[1];
  const float* Wl[3]  = {(const float*)d_in[2], (const float*)d_in[6], (const float*)d_in[10]};
  const float* asl[3] = {(const float*)d_in[3], (const float*)d_in[7], (const float*)d_in[11]};
  const float* adl[3] = {(const float*)d_in[4], (const float*)d_in[8], (const float*)d_in[12]};
  const float* bl[3]  = {(const float*)d_in[5], (const float*)d_in[9], (const float*)d_in[13]};
  float* out = (float*)d_out;

  char* p = (char*)d_ws;
  auto carve = [&](size_t bytes) {
    char* r = p;
    p += (bytes + 255) & ~size_t(255);
    return r;
  };
  int*   off     = (int*)carve(sizeof(int) * (N + 1));
  int*   cursor  = (int*)carve(sizeof(int) * N);
  int*   csr     = (int*)carve(sizeof(int) * Etot);
  float* a_s     = (float*)carve(sizeof(float) * N * 4);
  float* a_d     = (float*)carve(sizeof(float) * N * 4);
  bf16*  Wt      = (bf16*)carve(sizeof(bf16) * 3 * 65536);
  bf16*  h_buf   = (bf16*)carve(sizeof(bf16) * N * 256);
  bf16*  x_buf   = (bf16*)carve(sizeof(bf16) * N * 256);
  (void)ws_size; (void)n_in; (void)out_size;

  hipMemsetAsync(cursor, 0, sizeof(int) * N, stream);
  int eb = (Etot + 255) / 256;
  count_kernel<<<eb, 256, 0, stream>>>(ei, E, N, cursor);
  scan_kernel<<<1, 1024, 0, stream>>>(cursor, off, N);
  fill_kernel<<<eb, 256, 0, stream>>>(ei, E, N, cursor, csr);
  wt_kernel<<<dim3(16, 16, 3), 256, 0, stream>>>(Wl[0], Wl[1], Wl[2], Wt);

  dim3 ggrid((N + 63) / 64, 4);
  int ab = (N + 3) / 4;

  // layer 1 (fp32 input)
  gemm_mfma_kernel<true><<<ggrid, 256, 0, stream>>>(x, Wt, asl[0], adl[0],
                                                    h_buf, a_s, a_d, N);
  agg_fused_kernel<false><<<ab, 256, 0, stream>>>(h_buf, a_s, a_d, off, csr, bl[0],
                                                  x_buf, nullptr, N);
  // layer 2
  gemm_mfma_kernel<false><<<ggrid, 256, 0, stream>>>(x_buf, Wt + 65536, asl[1], adl[1],
                                                     h_buf, a_s, a_d, N);
  agg_fused_kernel<false><<<ab, 256, 0, stream>>>(h_buf, a_s, a_d, off, csr, bl[1],
                                                  x_buf, nullptr, N);
  // layer 3 (fp32 output)
  gemm_mfma_kernel<false><<<ggrid, 256, 0, stream>>>(x_buf, Wt + 131072, asl[2], adl[2],
                                                     h_buf, a_s, a_d, N);
  agg_fused_kernel<true><<<ab, 256, 0, stream>>>(h_buf, a_s, a_d, off, csr, bl[2],
                                                 nullptr, out, N);
}